// Round 1
// baseline (236.902 us; speedup 1.0000x reference)
//
#include <hip/hip_runtime.h>
#include <cstdint>

constexpr int B  = 4;
constexpr int C  = 128;
constexpr int CM = 32;        // mid channels
constexpr int H  = 160;
constexpr int W  = 160;
constexpr int HW = H * W;     // 25600
constexpr int HP = H + 1;     // 161
constexpr int WP = W + 1;     // 161
constexpr int PLANE = HP * WP; // 25921

// ---------------- K1: 1x1 conv (w1:[CM][C]) + BN1 raw stats ----------------
__global__ __launch_bounds__(256) void k_conv_stats(
    const float* __restrict__ x, const float* __restrict__ w1,
    float* __restrict__ h, double* __restrict__ stats1)
{
    __shared__ float wT[C * CM];       // transposed: wT[c*CM + o], 16 KB
    __shared__ float red[4][2 * CM];
    int tid = threadIdx.x;
    for (int i = tid; i < C * CM; i += 256) {
        int o = i / C, c = i % C;
        wT[c * CM + o] = w1[i];
    }
    __syncthreads();

    // 512 positions per block, 2 per thread. 25600 % 512 == 0 -> no b straddle.
    int gpos = blockIdx.x * 512 + tid * 2;
    int b = gpos / HW;
    int p = gpos % HW;
    const float* xb = x + ((size_t)b * C) * HW + p;

    float2 acc[CM];
    #pragma unroll
    for (int o = 0; o < CM; ++o) acc[o] = make_float2(0.f, 0.f);

    for (int c = 0; c < C; ++c) {
        float2 xv = *reinterpret_cast<const float2*>(xb + (size_t)c * HW);
        const float4* wrow = reinterpret_cast<const float4*>(&wT[c * CM]);
        #pragma unroll
        for (int j = 0; j < CM / 4; ++j) {
            float4 wv = wrow[j];
            acc[4*j+0].x = fmaf(wv.x, xv.x, acc[4*j+0].x);
            acc[4*j+0].y = fmaf(wv.x, xv.y, acc[4*j+0].y);
            acc[4*j+1].x = fmaf(wv.y, xv.x, acc[4*j+1].x);
            acc[4*j+1].y = fmaf(wv.y, xv.y, acc[4*j+1].y);
            acc[4*j+2].x = fmaf(wv.z, xv.x, acc[4*j+2].x);
            acc[4*j+2].y = fmaf(wv.z, xv.y, acc[4*j+2].y);
            acc[4*j+3].x = fmaf(wv.w, xv.x, acc[4*j+3].x);
            acc[4*j+3].y = fmaf(wv.w, xv.y, acc[4*j+3].y);
        }
    }

    float* hb = h + ((size_t)b * CM) * HW + p;
    int wave = tid >> 6, lane = tid & 63;
    #pragma unroll
    for (int o = 0; o < CM; ++o) {
        float2 a = acc[o];
        *reinterpret_cast<float2*>(hb + (size_t)o * HW) = a;
        float s  = a.x + a.y;
        float s2 = a.x * a.x + a.y * a.y;
        #pragma unroll
        for (int off = 32; off > 0; off >>= 1) {
            s  += __shfl_down(s,  off);
            s2 += __shfl_down(s2, off);
        }
        if (lane == 0) { red[wave][o] = s; red[wave][CM + o] = s2; }
    }
    __syncthreads();
    if (tid < 2 * CM) {
        float t = red[0][tid] + red[1][tid] + red[2][tid] + red[3][tid];
        atomicAdd(&stats1[tid], (double)t);
    }
}

// ---------------- K2: BN1 + ReLU + row cumsum into padded II ----------------
__global__ __launch_bounds__(256) void k_bn_rowscan(
    const float* __restrict__ h, const double* __restrict__ stats1,
    const float* __restrict__ g1, const float* __restrict__ b1,
    float* __restrict__ II)
{
    int r = blockIdx.x * 256 + threadIdx.x;   // row id over B*CM*H
    if (r >= B * CM * H) return;
    int y = r % H;
    int plane = r / H;
    int c = plane % CM;

    double n = (double)(B * HW);
    double mean = stats1[c] / n;
    double var  = stats1[CM + c] / n - mean * mean;
    float inv   = (float)(1.0 / sqrt(var + 1e-5));
    float scale = g1[c] * inv;
    float shift = b1[c] - (float)mean * scale;

    const float* hr = h + (size_t)plane * HW + (size_t)y * W;
    float* orow = II + ((size_t)plane * HP + (y + 1)) * WP;
    float run = 0.f;
    for (int xx = 0; xx < W; ++xx) {
        float v = fmaxf(fmaf(scale, hr[xx], shift), 0.f);
        run += v;
        orow[xx + 1] = run;
    }
}

// ---------------- K3: column cumsum in place ----------------
__global__ __launch_bounds__(256) void k_colscan(float* __restrict__ II)
{
    int idx = blockIdx.x * 256 + threadIdx.x;  // over B*CM planes x WP cols
    if (idx >= B * CM * WP) return;
    int xc = idx % WP;
    int plane = idx / WP;
    float* base = II + (size_t)plane * PLANE + xc;
    float run = 0.f;
    for (int y = 1; y <= H; ++y) {
        float* p = base + (size_t)y * WP;
        run += *p;
        *p = run;
    }
}

// ---------------- box evaluation helpers ----------------
struct Coord { int i0, i1; float a; };

__device__ inline Coord mk_coord(float base, float off)
{
    float u  = fminf(fmaxf(base + off, 0.f), 160.f);
    float uf = floorf(u);
    Coord cd;
    cd.a  = u - uf;
    cd.i0 = (int)uf;
    cd.i1 = min(cd.i0 + 1, 160);
    return cd;
}

__device__ inline float bilin(const float* __restrict__ P, const Coord& cu, const Coord& cv)
{
    const float* r0 = P + (size_t)cu.i0 * WP;
    const float* r1 = P + (size_t)cu.i1 * WP;
    float a = r0[cv.i0] * (1.f - cv.a) + r0[cv.i1] * cv.a;
    float b = r1[cv.i0] * (1.f - cv.a) + r1[cv.i1] * cv.a;
    return a * (1.f - cu.a) + b * cu.a;
}

__device__ inline float box_eval(const float* __restrict__ P, int y, int x,
                                 float ulo, float uhi, float vlo, float vhi)
{
    Coord cul = mk_coord((float)y, ulo);
    Coord cuh = mk_coord((float)y, uhi);
    Coord cvl = mk_coord((float)x, vlo);
    Coord cvh = mk_coord((float)x, vhi);
    return bilin(P, cuh, cvh) - bilin(P, cul, cvh)
         - bilin(P, cuh, cvl) + bilin(P, cul, cvl);
}

// ---------------- K4: box conv -> BN2 raw stats only ----------------
__global__ __launch_bounds__(256) void k_box_stats(
    const float* __restrict__ II,
    const float* __restrict__ xmin, const float* __restrict__ xmax,
    const float* __restrict__ ymin, const float* __restrict__ ymax,
    double* __restrict__ stats2)
{
    int k = blockIdx.y, b = blockIdx.z;
    int pos = blockIdx.x * 256 + threadIdx.x;
    int y = pos / W, xx = pos % W;
    const float* P = II + (size_t)(b * CM + (k >> 2)) * PLANE;

    float v = box_eval(P, y, xx, xmin[k], xmax[k] + 1.f, ymin[k], ymax[k] + 1.f);

    float s = v, s2 = v * v;
    #pragma unroll
    for (int off = 32; off > 0; off >>= 1) {
        s  += __shfl_down(s,  off);
        s2 += __shfl_down(s2, off);
    }
    __shared__ float red[4][2];
    int wave = threadIdx.x >> 6, lane = threadIdx.x & 63;
    if (lane == 0) { red[wave][0] = s; red[wave][1] = s2; }
    __syncthreads();
    if (threadIdx.x == 0) {
        atomicAdd(&stats2[k],     (double)(red[0][0] + red[1][0] + red[2][0] + red[3][0]));
        atomicAdd(&stats2[C + k], (double)(red[0][1] + red[1][1] + red[2][1] + red[3][1]));
    }
}

// ---------------- K5: re-evaluate box, BN2, relu(x + h) ----------------
__global__ __launch_bounds__(256) void k_box_final(
    const float* __restrict__ II, const float* __restrict__ x,
    const float* __restrict__ xmin, const float* __restrict__ xmax,
    const float* __restrict__ ymin, const float* __restrict__ ymax,
    const float* __restrict__ g2, const float* __restrict__ b2,
    const double* __restrict__ stats2, float* __restrict__ out)
{
    int k = blockIdx.y, b = blockIdx.z;
    int pos = blockIdx.x * 256 + threadIdx.x;

    __shared__ float ss[2];
    if (threadIdx.x == 0) {
        double n = (double)(B * HW);
        double mean = stats2[k] / n;
        double var  = stats2[C + k] / n - mean * mean;
        float inv   = (float)(1.0 / sqrt(var + 1e-5));
        float scale = g2[k] * inv;
        ss[0] = scale;
        ss[1] = b2[k] - (float)mean * scale;
    }
    __syncthreads();

    int y = pos / W, xx = pos % W;
    const float* P = II + (size_t)(b * CM + (k >> 2)) * PLANE;
    float v = box_eval(P, y, xx, xmin[k], xmax[k] + 1.f, ymin[k], ymax[k] + 1.f);

    size_t idx = ((size_t)(b * C + k)) * HW + pos;
    out[idx] = fmaxf(x[idx] + fmaf(ss[0], v, ss[1]), 0.f);
}

// ---------------- launch ----------------
extern "C" void kernel_launch(void* const* d_in, const int* in_sizes, int n_in,
                              void* d_out, int out_size, void* d_ws, size_t ws_size,
                              hipStream_t stream)
{
    const float* x    = (const float*)d_in[0];
    const float* w1   = (const float*)d_in[1];
    const float* g1   = (const float*)d_in[2];
    const float* b1   = (const float*)d_in[3];
    const float* xmin = (const float*)d_in[4];
    const float* xmax = (const float*)d_in[5];
    const float* ymin = (const float*)d_in[6];
    const float* ymax = (const float*)d_in[7];
    const float* g2   = (const float*)d_in[8];
    const float* b2   = (const float*)d_in[9];
    float* out = (float*)d_out;

    char* ws = (char*)d_ws;
    double* stats1 = (double*)ws;            // [0..63]   sums / sumsq (CM)
    double* stats2 = (double*)ws + 64;       // [64..319] sums / sumsq (C)
    float* h  = (float*)(ws + 4096);
    float* II = (float*)(ws + 4096 + (size_t)B * CM * HW * sizeof(float));

    hipMemsetAsync(ws, 0, 320 * sizeof(double), stream);
    hipMemsetAsync(II, 0, (size_t)B * CM * PLANE * sizeof(float), stream);

    k_conv_stats<<<dim3(B * HW / 512), 256, 0, stream>>>(x, w1, h, stats1);
    k_bn_rowscan<<<dim3((B * CM * H + 255) / 256), 256, 0, stream>>>(h, stats1, g1, b1, II);
    k_colscan  <<<dim3((B * CM * WP + 255) / 256), 256, 0, stream>>>(II);
    k_box_stats<<<dim3(HW / 256, C, B), 256, 0, stream>>>(II, xmin, xmax, ymin, ymax, stats2);
    k_box_final<<<dim3(HW / 256, C, B), 256, 0, stream>>>(II, x, xmin, xmax, ymin, ymax,
                                                          g2, b2, stats2, out);
}

// Round 2
// 144.564 us; speedup vs baseline: 1.6387x; 1.6387x over previous
//
#include <hip/hip_runtime.h>
#include <cstdint>

constexpr int B  = 4;
constexpr int C  = 128;
constexpr int CM = 32;        // mid channels
constexpr int H  = 160;
constexpr int W  = 160;
constexpr int HW = H * W;     // 25600
constexpr int HP = H + 1;     // 161
constexpr int WP = W + 1;     // 161
constexpr int PLANE = HP * WP; // 25921
constexpr int TY = 16;         // rows per box tile
constexpr int NTILE = H / TY;  // 10

// ---------------- K1: 1x1 conv (w1:[CM][C]) + BN1 raw stats ----------------
__global__ __launch_bounds__(256) void k_conv_stats(
    const float* __restrict__ x, const float* __restrict__ w1,
    float* __restrict__ h, double* __restrict__ stats1)
{
    __shared__ float wT[C * CM];       // transposed: wT[c*CM + o], 16 KB
    __shared__ float red[4][2 * CM];
    int tid = threadIdx.x;
    for (int i = tid; i < C * CM; i += 256) {
        int o = i / C, c = i % C;
        wT[c * CM + o] = w1[i];
    }
    __syncthreads();

    // 512 positions per block, 2 per thread. 25600 % 512 == 0 -> no b straddle.
    int gpos = blockIdx.x * 512 + tid * 2;
    int b = gpos / HW;
    int p = gpos % HW;
    const float* xb = x + ((size_t)b * C) * HW + p;

    float2 acc[CM];
    #pragma unroll
    for (int o = 0; o < CM; ++o) acc[o] = make_float2(0.f, 0.f);

    for (int c = 0; c < C; ++c) {
        float2 xv = *reinterpret_cast<const float2*>(xb + (size_t)c * HW);
        const float4* wrow = reinterpret_cast<const float4*>(&wT[c * CM]);
        #pragma unroll
        for (int j = 0; j < CM / 4; ++j) {
            float4 wv = wrow[j];
            acc[4*j+0].x = fmaf(wv.x, xv.x, acc[4*j+0].x);
            acc[4*j+0].y = fmaf(wv.x, xv.y, acc[4*j+0].y);
            acc[4*j+1].x = fmaf(wv.y, xv.x, acc[4*j+1].x);
            acc[4*j+1].y = fmaf(wv.y, xv.y, acc[4*j+1].y);
            acc[4*j+2].x = fmaf(wv.z, xv.x, acc[4*j+2].x);
            acc[4*j+2].y = fmaf(wv.z, xv.y, acc[4*j+2].y);
            acc[4*j+3].x = fmaf(wv.w, xv.x, acc[4*j+3].x);
            acc[4*j+3].y = fmaf(wv.w, xv.y, acc[4*j+3].y);
        }
    }

    float* hb = h + ((size_t)b * CM) * HW + p;
    int wave = tid >> 6, lane = tid & 63;
    #pragma unroll
    for (int o = 0; o < CM; ++o) {
        float2 a = acc[o];
        *reinterpret_cast<float2*>(hb + (size_t)o * HW) = a;
        float s  = a.x + a.y;
        float s2 = a.x * a.x + a.y * a.y;
        #pragma unroll
        for (int off = 32; off > 0; off >>= 1) {
            s  += __shfl_down(s,  off);
            s2 += __shfl_down(s2, off);
        }
        if (lane == 0) { red[wave][o] = s; red[wave][CM + o] = s2; }
    }
    __syncthreads();
    if (tid < 2 * CM) {
        float t = red[0][tid] + red[1][tid] + red[2][tid] + red[3][tid];
        atomicAdd(&stats1[tid], (double)t);
    }
}

// -------- K2: BN1 + ReLU + row cumsum (wave-per-row shuffle scan) --------
__global__ __launch_bounds__(256) void k_bn_rowscan(
    const float* __restrict__ h, const double* __restrict__ stats1,
    const float* __restrict__ g1, const float* __restrict__ b1,
    float* __restrict__ II)
{
    int wave = threadIdx.x >> 6, lane = threadIdx.x & 63;
    int r = blockIdx.x * 4 + wave;     // row id over B*CM*H = 20480 (divisible by 4)
    int y = r % H;
    int plane = r / H;
    int c = plane % CM;

    double n = (double)(B * HW);
    double mean = stats1[c] / n;
    double var  = stats1[CM + c] / n - mean * mean;
    float inv   = (float)(1.0 / sqrt(var + 1e-5));
    float scale = g1[c] * inv;
    float shift = b1[c] - (float)mean * scale;

    const float* hr = h + (size_t)plane * HW + (size_t)y * W;
    float* orow = II + ((size_t)plane * HP + (y + 1)) * WP;

    float carry = 0.f;
    #pragma unroll
    for (int x0 = 0; x0 < W; x0 += 64) {
        int xx = x0 + lane;
        float v = (xx < W) ? fmaxf(fmaf(scale, hr[xx], shift), 0.f) : 0.f;
        #pragma unroll
        for (int off = 1; off < 64; off <<= 1) {
            float t = __shfl_up(v, off);
            if (lane >= off) v += t;
        }
        v += carry;
        if (xx < W) orow[xx + 1] = v;
        carry = __shfl(v, 63);
    }
}

// ---------------- K3: column cumsum in place ----------------
__global__ __launch_bounds__(256) void k_colscan(float* __restrict__ II)
{
    int idx = blockIdx.x * 256 + threadIdx.x;  // over B*CM planes x WP cols
    if (idx >= B * CM * WP) return;
    int xc = idx % WP;
    int plane = idx / WP;
    float* base = II + (size_t)plane * PLANE + xc;
    float run = 0.f;
    #pragma unroll 4
    for (int y = 1; y <= H; ++y) {
        float* p = base + (size_t)y * WP;
        run += *p;
        *p = run;
    }
}

// ---------------- box tile machinery ----------------
struct BoxSmem {
    float D[TY][WP];      // row-interp difference rows
    int   ru0[2][TY];     // [0]=lo, [1]=hi row coords
    int   ru1[2][TY];
    float rua[2][TY];
    int   cv0[2][W];      // col coords ([0]=lo, [1]=hi)
    float cva[2][W];
};

__device__ inline void fill_D(BoxSmem& sm, const float* __restrict__ II,
    int tile, int k, int b,
    const float* __restrict__ xmin, const float* __restrict__ xmax,
    const float* __restrict__ ymin, const float* __restrict__ ymax)
{
    int tid = threadIdx.x;
    if (tid < 2 * TY) {
        int side = tid / TY, ty = tid % TY;
        float off = side ? (xmax[k] + 1.f) : xmin[k];
        float u = fminf(fmaxf((float)(tile * TY + ty) + off, 0.f), 160.f);
        float uf = floorf(u);
        int i0 = (int)uf;
        sm.ru0[side][ty] = i0;
        sm.ru1[side][ty] = min(i0 + 1, 160);
        sm.rua[side][ty] = u - uf;
    }
    for (int e = tid; e < 2 * W; e += 256) {
        int side = e / W, xx = e % W;
        float off = side ? (ymax[k] + 1.f) : ymin[k];
        float v = fminf(fmaxf((float)xx + off, 0.f), 160.f);
        float vf = floorf(v);
        sm.cv0[side][xx] = (int)vf;
        sm.cva[side][xx] = v - vf;
    }
    __syncthreads();

    const float* P = II + (size_t)(b * CM + (k >> 2)) * PLANE;
    for (int e = tid; e < TY * WP; e += 256) {
        int ty = e / WP, v = e % WP;
        float al = sm.rua[0][ty], ah = sm.rua[1][ty];
        float lo = P[(size_t)sm.ru0[0][ty] * WP + v] * (1.f - al)
                 + P[(size_t)sm.ru1[0][ty] * WP + v] * al;
        float hi = P[(size_t)sm.ru0[1][ty] * WP + v] * (1.f - ah)
                 + P[(size_t)sm.ru1[1][ty] * WP + v] * ah;
        sm.D[ty][v] = hi - lo;
    }
    __syncthreads();
}

__device__ inline float eval_D(const BoxSmem& sm, int ty, int xx)
{
    int   l0 = sm.cv0[0][xx];
    float la = sm.cva[0][xx];
    int   l1 = min(l0 + 1, 160);
    int   h0 = sm.cv0[1][xx];
    float ha = sm.cva[1][xx];
    int   h1 = min(h0 + 1, 160);
    const float* Dr = sm.D[ty];
    return (Dr[h0] * (1.f - ha) + Dr[h1] * ha)
         - (Dr[l0] * (1.f - la) + Dr[l1] * la);
}

// ---------------- K4: box conv -> BN2 raw stats only ----------------
__global__ __launch_bounds__(256) void k_box_stats(
    const float* __restrict__ II,
    const float* __restrict__ xmin, const float* __restrict__ xmax,
    const float* __restrict__ ymin, const float* __restrict__ ymax,
    double* __restrict__ stats2)
{
    __shared__ BoxSmem sm;
    __shared__ float red[4][2];
    int tile = blockIdx.x, k = blockIdx.y, b = blockIdx.z;
    fill_D(sm, II, tile, k, b, xmin, xmax, ymin, ymax);

    float s = 0.f, s2 = 0.f;
    for (int o = threadIdx.x; o < TY * W; o += 256) {
        int ty = o / W, xx = o % W;
        float v = eval_D(sm, ty, xx);
        s  += v;
        s2 += v * v;
    }
    #pragma unroll
    for (int off = 32; off > 0; off >>= 1) {
        s  += __shfl_down(s,  off);
        s2 += __shfl_down(s2, off);
    }
    int wave = threadIdx.x >> 6, lane = threadIdx.x & 63;
    if (lane == 0) { red[wave][0] = s; red[wave][1] = s2; }
    __syncthreads();
    if (threadIdx.x == 0) {
        atomicAdd(&stats2[k],     (double)(red[0][0] + red[1][0] + red[2][0] + red[3][0]));
        atomicAdd(&stats2[C + k], (double)(red[0][1] + red[1][1] + red[2][1] + red[3][1]));
    }
}

// ---------------- K5: box conv again, BN2, relu(x + h) ----------------
__global__ __launch_bounds__(256) void k_box_final(
    const float* __restrict__ II, const float* __restrict__ x,
    const float* __restrict__ xmin, const float* __restrict__ xmax,
    const float* __restrict__ ymin, const float* __restrict__ ymax,
    const float* __restrict__ g2, const float* __restrict__ b2,
    const double* __restrict__ stats2, float* __restrict__ out)
{
    __shared__ BoxSmem sm;
    __shared__ float ss[2];
    int tile = blockIdx.x, k = blockIdx.y, b = blockIdx.z;

    if (threadIdx.x == 0) {
        double n = (double)(B * HW);
        double mean = stats2[k] / n;
        double var  = stats2[C + k] / n - mean * mean;
        float inv   = (float)(1.0 / sqrt(var + 1e-5));
        float scale = g2[k] * inv;
        ss[0] = scale;
        ss[1] = b2[k] - (float)mean * scale;
    }
    fill_D(sm, II, tile, k, b, xmin, xmax, ymin, ymax);  // syncs cover ss

    float scale = ss[0], shift = ss[1];
    size_t base = ((size_t)(b * C + k)) * HW + (size_t)tile * TY * W;
    for (int o = threadIdx.x; o < TY * W; o += 256) {
        int ty = o / W, xx = o % W;
        float v = eval_D(sm, ty, xx);
        size_t idx = base + (size_t)ty * W + xx;
        out[idx] = fmaxf(x[idx] + fmaf(scale, v, shift), 0.f);
    }
}

// ---------------- launch ----------------
extern "C" void kernel_launch(void* const* d_in, const int* in_sizes, int n_in,
                              void* d_out, int out_size, void* d_ws, size_t ws_size,
                              hipStream_t stream)
{
    const float* x    = (const float*)d_in[0];
    const float* w1   = (const float*)d_in[1];
    const float* g1   = (const float*)d_in[2];
    const float* b1   = (const float*)d_in[3];
    const float* xmin = (const float*)d_in[4];
    const float* xmax = (const float*)d_in[5];
    const float* ymin = (const float*)d_in[6];
    const float* ymax = (const float*)d_in[7];
    const float* g2   = (const float*)d_in[8];
    const float* b2   = (const float*)d_in[9];
    float* out = (float*)d_out;

    char* ws = (char*)d_ws;
    double* stats1 = (double*)ws;            // [0..63]   sums / sumsq (CM)
    double* stats2 = (double*)ws + 64;       // [64..319] sums / sumsq (C)
    float* h  = (float*)(ws + 4096);
    float* II = (float*)(ws + 4096 + (size_t)B * CM * HW * sizeof(float));

    hipMemsetAsync(ws, 0, 320 * sizeof(double), stream);
    hipMemsetAsync(II, 0, (size_t)B * CM * PLANE * sizeof(float), stream);

    k_conv_stats<<<dim3(B * HW / 512), 256, 0, stream>>>(x, w1, h, stats1);
    k_bn_rowscan<<<dim3(B * CM * H / 4), 256, 0, stream>>>(h, stats1, g1, b1, II);
    k_colscan  <<<dim3((B * CM * WP + 255) / 256), 256, 0, stream>>>(II);
    k_box_stats<<<dim3(NTILE, C, B), 256, 0, stream>>>(II, xmin, xmax, ymin, ymax, stats2);
    k_box_final<<<dim3(NTILE, C, B), 256, 0, stream>>>(II, x, xmin, xmax, ymin, ymax,
                                                       g2, b2, stats2, out);
}